// Round 6
// baseline (121.158 us; speedup 1.0000x reference)
//
#include <hip/hip_runtime.h>
#include <cmath>

#define THREADS 256
#define NCELL 10
#define DDIM 9

typedef float f32x2 __attribute__((ext_vector_type(2)));

__device__ __forceinline__ f32x2 mk2(float a, float b) { f32x2 r; r[0] = a; r[1] = b; return r; }
__device__ __forceinline__ f32x2 fma2(f32x2 a, f32x2 b, f32x2 c) {
  return __builtin_elementwise_fma(a, b, c);   // v_pk_fma_f32 on gfx950
}
__device__ __forceinline__ f32x2 max2(f32x2 a, f32x2 b) {
  return __builtin_elementwise_max(a, b);      // v_pk_max_f32
}

struct Basis { float Bt[DDIM][2 * NCELL]; }; // Bt[t][l] = B[l][t]

// Reproduce numpy.linalg.svd(L) Vt[11:] rows: LAPACK dgesdd Path 4t leaves
// rows m..n-1 of VT equal to the LQ-factorization orthogonal complement
// (dgelqf + dorglq). Replicate dlarfg/dgelq2/dorgl2 in double precision.
static void compute_basis_host(Basis* bs) {
  double L[11][20];
  for (int r = 0; r < 11; ++r)
    for (int c = 0; c < 20; ++c) L[r][c] = 0.0;
  for (int k = 1; k < NCELL; ++k) {
    double xk = (double)k / (double)NCELL;
    L[k - 1][2 * (k - 1)] = xk;
    L[k - 1][2 * (k - 1) + 1] = 1.0;
    L[k - 1][2 * k] = -xk;
    L[k - 1][2 * k + 1] = -1.0;
  }
  L[NCELL - 1][1] = 1.0;
  L[NCELL][2 * (NCELL - 1)] = 1.0;
  L[NCELL][2 * (NCELL - 1) + 1] = 1.0;

  double v[11][20];
  double tau[11];
  for (int i = 0; i < 11; ++i) {
    double alpha = L[i][i];
    double xn2 = 0.0;
    for (int l = i + 1; l < 20; ++l) xn2 += L[i][l] * L[i][l];
    double xnorm = sqrt(xn2);
    for (int l = 0; l < 20; ++l) v[i][l] = 0.0;
    v[i][i] = 1.0;
    if (xnorm == 0.0) {
      tau[i] = 0.0;
    } else {
      double beta = sqrt(alpha * alpha + xn2);
      if (alpha >= 0.0) beta = -beta;        // dlarfg: beta = -sign(alpha)*norm
      tau[i] = (beta - alpha) / beta;
      double sc = 1.0 / (alpha - beta);
      for (int l = i + 1; l < 20; ++l) v[i][l] = L[i][l] * sc;
      L[i][i] = beta;
      for (int j = i + 1; j < 11; ++j) {
        double w = 0.0;
        for (int l = i; l < 20; ++l) w += L[j][l] * v[i][l];
        w *= tau[i];
        for (int l = i; l < 20; ++l) L[j][l] -= w * v[i][l];
      }
    }
  }
  for (int j = 11; j < 20; ++j) {
    double q[20];
    for (int l = 0; l < 20; ++l) q[l] = 0.0;
    q[j] = 1.0;
    for (int i = 10; i >= 0; --i) {
      double w = 0.0;
      for (int l = i; l < 20; ++l) w += v[i][l] * q[l];
      w *= tau[i];
      for (int l = i; l < 20; ++l) q[l] -= w * v[i][l];
    }
    for (int l = 0; l < 20; ++l) bs->Bt[j - 11][l] = (float)q[l];
  }
}

// Fold W3B[r][l] = sum_t w3[r*9+t]*Bt[t][l] (10x20) and b3B[l] = sum_t b3[t]*Bt[t][l]
// per MLP into ws: [m1: 200 W + 20 b][m2: 200 W + 20 b] floats.
__global__ void fold_kernel(const float* __restrict__ w3_1, const float* __restrict__ b3_1,
                            const float* __restrict__ w3_2, const float* __restrict__ b3_2,
                            float* __restrict__ ws, Basis bb) {
  for (int f = threadIdx.x; f < 440; f += THREADS) {
    int m = f / 220;
    int j = f % 220;
    const float* w3 = (m == 0) ? w3_1 : w3_2;
    const float* b3 = (m == 0) ? b3_1 : b3_2;
    float val = 0.0f;
    if (j < 200) {
      int r = j / 20, l = j % 20;
      for (int t = 0; t < DDIM; ++t) val += w3[r * DDIM + t] * bb.Bt[t][l];
    } else {
      int l = j - 200;
      for (int t = 0; t < DDIM; ++t) val += b3[t] * bb.Bt[t][l];
    }
    ws[f] = val;
  }
}

// MLP (1->10->10->10) then A = h2 @ W3B + b3B; (a,b) per cell kept in registers.
__device__ __forceinline__ void mlp_A(float xin,
    const float* __restrict__ w0, const float* __restrict__ b0,
    const float* __restrict__ w1, const float* __restrict__ b1,
    const float* __restrict__ w2, const float* __restrict__ b2,
    const float* __restrict__ wbf,     // 220 floats: 100 f32x2 W3B pairs + 10 f32x2 b3B pairs
    f32x2 acc[NCELL]) {
  const f32x2* w0p = (const f32x2*)w0;
  const f32x2* b0p = (const f32x2*)b0;
  const f32x2* w1p = (const f32x2*)w1;
  const f32x2* b1p = (const f32x2*)b1;
  const f32x2* w2p = (const f32x2*)w2;
  const f32x2* b2p = (const f32x2*)b2;
  const f32x2* WB  = (const f32x2*)wbf;

  f32x2 h0[5], h1[5], h2[5];
  f32x2 xx = mk2(xin, xin);
#pragma unroll
  for (int p = 0; p < 5; ++p) h0[p] = fma2(xx, w0p[p], b0p[p]);

#pragma unroll
  for (int p = 0; p < 5; ++p) h1[p] = b1p[p];
#pragma unroll
  for (int r = 0; r < 10; ++r) {
    float h = h0[r >> 1][r & 1];
    f32x2 hh = mk2(h, h);
#pragma unroll
    for (int p = 0; p < 5; ++p) h1[p] = fma2(hh, w1p[r * 5 + p], h1[p]);
  }
  f32x2 zero = mk2(0.0f, 0.0f);
#pragma unroll
  for (int p = 0; p < 5; ++p) h1[p] = max2(h1[p], zero);

#pragma unroll
  for (int p = 0; p < 5; ++p) h2[p] = b2p[p];
#pragma unroll
  for (int r = 0; r < 10; ++r) {
    float h = h1[r >> 1][r & 1];
    f32x2 hh = mk2(h, h);
#pragma unroll
    for (int p = 0; p < 5; ++p) h2[p] = fma2(hh, w2p[r * 5 + p], h2[p]);
  }
#pragma unroll
  for (int p = 0; p < 5; ++p) h2[p] = max2(h2[p], zero);

#pragma unroll
  for (int l = 0; l < NCELL; ++l) acc[l] = WB[100 + l];   // b3B pairs
#pragma unroll
  for (int r = 0; r < 10; ++r) {
    float h = h2[r >> 1][r & 1];
    f32x2 hh = mk2(h, h);
#pragma unroll
    for (int l = 0; l < NCELL; ++l) acc[l] = fma2(hh, WB[r * 10 + l], acc[l]);
  }
}

// Closed-form CPA flow. Monotone trajectory => visited cells are a consecutive
// run from c0 in direction sign(v0). Per-cell traversal times tau_j and
// log-derivative contributions lr_j = log(v_far/v_near) are all independent;
// prefix sums + static select chains replace the serial hop loop. Guards
// (1e-10 lin, 1e-30 ratio clamp, 1e-14 dead-v) mirror the reference; tau is
// clamped to [0,16] (crossing needs tau < 1, so the cap is semantically inert
// and keeps blocked-cell sentinels cancellation-safe in the prefix sums).
__device__ __forceinline__ void flow_closed(float phi0, const f32x2 acc[NCELL],
                                            float& zo, float& ldo) {
  int c0 = (int)(phi0 * 10.0f);
  c0 = c0 < 0 ? 0 : (c0 > 9 ? 9 : c0);

  // (a,b) at starting cell
  f32x2 ab0 = acc[0];
#pragma unroll
  for (int k = 1; k < NCELL; ++k) ab0 = (c0 == k) ? acc[k] : ab0;
  float a0 = ab0[0], b0 = ab0[1];
  float v0 = fmaf(a0, phi0, b0);
  bool right = (v0 >= 0.0f);
  float d01 = right ? 0.1f : -0.1f;

  // first (partial) cell: time/log-ratio to its exit boundary
  float xexit0 = (right ? (float)(c0 + 1) : (float)c0) * 0.1f;
  bool lin0 = fabsf(a0) < 1e-10f;
  float rsa0 = __builtin_amdgcn_rcpf(lin0 ? 1.0f : a0);
  float vf0 = fmaf(a0, xexit0, b0);
  float ratio0 = vf0 * __builtin_amdgcn_rcpf(v0);
  float l0 = __logf(fmaxf(ratio0, 1e-30f));
  float sb0 = (fabsf(b0) < 1e-30f) ? 1.0f : b0;
  float tf = lin0 ? ((xexit0 - phi0) * __builtin_amdgcn_rcpf(sb0)) : (l0 * rsa0);
  bool bad0 = fabsf(v0) < 1e-14f;
  tf = bad0 ? 16.0f : fminf(fmaxf(tf, 0.0f), 16.0f);
  float lr0 = lin0 ? (a0 * tf) : l0;
  lr0 = bad0 ? 0.0f : lr0;

  // per-cell quantities (all independent -> full ILP)
  float tauA[NCELL], lrA[NCELL], vnA[NCELL];
#pragma unroll
  for (int k = 0; k < NCELL; ++k) {
    float a = acc[k][0], b = acc[k][1];
    float vL = fmaf(a, (float)k * 0.1f, b);
    float vR = fmaf(a, (float)(k + 1) * 0.1f, b);
    float vn = right ? vL : vR;
    float vf = right ? vR : vL;
    vnA[k] = vn;
    bool lin = fabsf(a) < 1e-10f;
    float rsa = __builtin_amdgcn_rcpf(lin ? 1.0f : a);
    float ratio = vf * __builtin_amdgcn_rcpf(vn);
    float l = __logf(fmaxf(ratio, 1e-30f));
    float sb = (fabsf(b) < 1e-30f) ? 1.0f : b;
    float tk = lin ? (d01 * __builtin_amdgcn_rcpf(sb)) : (l * rsa);
    // blocked: dead v at entry, or entry velocity opposes travel direction
    bool bad = (fabsf(vn) < 1e-14f) || (right ? (vn < 0.0f) : (vn > 0.0f));
    tk = bad ? 16.0f : fminf(fmaxf(tk, 0.0f), 16.0f);
    float lk = lin ? (a * tk) : l;        // uses clamped tk: bounded
    tauA[k] = tk;
    lrA[k] = bad ? 0.0f : lk;
  }

  // prefix sums of {tau, lr} (packed)
  f32x2 P[NCELL];
  P[0] = mk2(tauA[0], lrA[0]);
#pragma unroll
  for (int k = 1; k < NCELL; ++k) P[k] = P[k - 1] + mk2(tauA[k], lrA[k]);

  // window bases at c0
  f32x2 Pc0 = P[0];
  f32x2 TL0 = mk2(tauA[0], lrA[0]);
#pragma unroll
  for (int k = 1; k < NCELL; ++k) {
    bool e = (c0 == k);
    Pc0 = e ? P[k] : Pc0;
    TL0 = e ? mk2(tauA[k], lrA[k]) : TL0;
  }
  f32x2 baseR = Pc0;           // right: W_k = P[k-1] - baseR
  f32x2 baseL = Pc0 - TL0;     // left:  W_k = baseL - P[k]

  // enter-times and crossing flags (monotone in travel order)
  bool crossed[NCELL];
  float TkA[NCELL], LDkA[NCELL];
#pragma unroll
  for (int k = 0; k < NCELL; ++k) {
    f32x2 Pm1 = (k == 0) ? mk2(0.0f, 0.0f) : P[k - 1];
    f32x2 WR = Pm1 - baseR;
    f32x2 WL = baseL - P[k];
    f32x2 W = right ? WR : WL;
    TkA[k] = tf + W[0];
    LDkA[k] = lr0 + W[1];
    bool reach = right ? (k > c0) : (k < c0);
    crossed[k] = reach && (TkA[k] < 1.0f);
  }

  // unique final cell via is_last (= crossed & next-in-direction not crossed)
  float t_rem = 1.0f, ld_pre = 0.0f, v_e = v0;
  f32x2 TLf = mk2(tf, lr0);
  f32x2 ABf = ab0;
  f32x2 XXf = mk2(phi0, xexit0);   // {enter point, exit boundary}
#pragma unroll
  for (int k = 0; k < NCELL; ++k) {
    bool nb = right ? ((k < 9) ? crossed[k + 1] : false)
                    : ((k > 0) ? crossed[k - 1] : false);
    bool is_last = crossed[k] && !nb;
    t_rem = is_last ? (1.0f - TkA[k]) : t_rem;
    ld_pre = is_last ? LDkA[k] : ld_pre;
    v_e = is_last ? vnA[k] : v_e;
    TLf = is_last ? mk2(tauA[k], lrA[k]) : TLf;
    ABf = is_last ? acc[k] : ABf;
    f32x2 XR = mk2((float)k * 0.1f, (float)(k + 1) * 0.1f);
    f32x2 XL = mk2((float)(k + 1) * 0.1f, (float)k * 0.1f);
    XXf = is_last ? (right ? XR : XL) : XXf;
  }

  // evolve within final cell for t_rem (reference's phi_exp/phi_lin formulas)
  float a_f = ABf[0], b_f = ABf[1];
  bool linf = fabsf(a_f) < 1e-10f;
  float rsaf = __builtin_amdgcn_rcpf(linf ? 1.0f : a_f);
  float bsa = b_f * rsaf;
  float E = __expf(a_f * t_rem);
  float x_e = XXf[0];
  float phi_nl = fmaf(x_e + bsa, E, -bsa);
  float phi_li = fmaf(b_f, t_rem, x_e);
  float phi1 = linf ? phi_li : phi_nl;
  bool exits = TLf[0] < t_rem;     // leaves final cell (grid edge): snap to boundary
  phi1 = exits ? XXf[1] : phi1;
  zo = phi1;
  ldo = ld_pre + (exits ? TLf[1] : a_f * t_rem);
}

__global__ __launch_bounds__(THREADS, 4) void cpab2d_kernel(
    const float* __restrict__ x,
    const float* __restrict__ m1w0, const float* __restrict__ m1b0,
    const float* __restrict__ m1w1, const float* __restrict__ m1b1,
    const float* __restrict__ m1w2, const float* __restrict__ m1b2,
    const float* __restrict__ m2w0, const float* __restrict__ m2b0,
    const float* __restrict__ m2w1, const float* __restrict__ m2b1,
    const float* __restrict__ m2w2, const float* __restrict__ m2b2,
    const float* __restrict__ wsf,
    float* __restrict__ out, int n) {
  int i = blockIdx.x * THREADS + threadIdx.x;
  if (i >= n) return;

  float2 xi = reinterpret_cast<const float2*>(x)[i];
  // xs = x[:, [1,0]]: x1 = x[:,1], x2 = x[:,0]; both clipped first
  float x2v = fminf(fmaxf(xi.x, 1e-7f), 1.0f - 1e-7f);
  float x1v = fminf(fmaxf(xi.y, 1e-7f), 1.0f - 1e-7f);

  f32x2 acc[NCELL];

  // theta2 = mlp(x1, m2); z2,g2 = flow(x2, theta2)
  mlp_A(x1v, m2w0, m2b0, m2w1, m2b1, m2w2, m2b2, wsf + 220, acc);
  float z2, ld2;
  flow_closed(x2v, acc, z2, ld2);

  // theta1 = mlp(z2, m1); z1,g1 = flow(x1, theta1)
  mlp_A(z2, m1w0, m1b0, m1w1, m1b1, m1w2, m1b2, wsf, acc);
  float z1, ld1;
  flow_closed(x1v, acc, z1, ld1);

  // z = [z2, z1]; log_dz_dx = [ld2, ld1]
  reinterpret_cast<float2*>(out)[i] = make_float2(z2, z1);
  reinterpret_cast<float2*>(out + 2 * (size_t)n)[i] = make_float2(ld2, ld1);
}

extern "C" void kernel_launch(void* const* d_in, const int* in_sizes, int n_in,
                              void* d_out, int out_size, void* d_ws, size_t ws_size,
                              hipStream_t stream) {
  const float* x    = (const float*)d_in[0];
  const float* m1w0 = (const float*)d_in[1];
  const float* m1b0 = (const float*)d_in[2];
  const float* m1w1 = (const float*)d_in[3];
  const float* m1b1 = (const float*)d_in[4];
  const float* m1w2 = (const float*)d_in[5];
  const float* m1b2 = (const float*)d_in[6];
  const float* m1w3 = (const float*)d_in[7];
  const float* m1b3 = (const float*)d_in[8];
  const float* m2w0 = (const float*)d_in[9];
  const float* m2b0 = (const float*)d_in[10];
  const float* m2w1 = (const float*)d_in[11];
  const float* m2b1 = (const float*)d_in[12];
  const float* m2w2 = (const float*)d_in[13];
  const float* m2b2 = (const float*)d_in[14];
  const float* m2w3 = (const float*)d_in[15];
  const float* m2b3 = (const float*)d_in[16];
  float* out = (float*)d_out;
  float* wsf = (float*)d_ws;
  int n = in_sizes[0] / 2;

  Basis bs;
  compute_basis_host(&bs);

  fold_kernel<<<1, THREADS, 0, stream>>>(m1w3, m1b3, m2w3, m2b3, wsf, bs);

  dim3 grid((n + THREADS - 1) / THREADS), block(THREADS);
  cpab2d_kernel<<<grid, block, 0, stream>>>(
      x, m1w0, m1b0, m1w1, m1b1, m1w2, m1b2,
      m2w0, m2b0, m2w1, m2b1, m2w2, m2b2,
      wsf, out, n);
}

// Round 7
// 57.035 us; speedup vs baseline: 2.1243x; 2.1243x over previous
//
#include <hip/hip_runtime.h>
#include <cmath>

#define THREADS 256
#define NCELL 10
#define DDIM 9

typedef float f32x2 __attribute__((ext_vector_type(2)));

__device__ __forceinline__ f32x2 fma2(f32x2 a, f32x2 b, f32x2 c) {
  return __builtin_elementwise_fma(a, b, c);   // v_pk_fma_f32 on gfx950
}
__device__ __forceinline__ f32x2 max2(f32x2 a, f32x2 b) {
  return __builtin_elementwise_max(a, b);      // v_pk_max_f32
}

struct Basis { float Bt[DDIM][2 * NCELL]; }; // Bt[t][l] = B[l][t]

// Reproduce numpy.linalg.svd(L) Vt[11:] rows: LAPACK dgesdd Path 4t leaves
// rows m..n-1 of VT equal to the LQ-factorization orthogonal complement
// (dgelqf + dorglq). Replicate dlarfg/dgelq2/dorgl2 in double precision.
static void compute_basis_host(Basis* bs) {
  double L[11][20];
  for (int r = 0; r < 11; ++r)
    for (int c = 0; c < 20; ++c) L[r][c] = 0.0;
  for (int k = 1; k < NCELL; ++k) {
    double xk = (double)k / (double)NCELL;
    L[k - 1][2 * (k - 1)] = xk;
    L[k - 1][2 * (k - 1) + 1] = 1.0;
    L[k - 1][2 * k] = -xk;
    L[k - 1][2 * k + 1] = -1.0;
  }
  L[NCELL - 1][1] = 1.0;
  L[NCELL][2 * (NCELL - 1)] = 1.0;
  L[NCELL][2 * (NCELL - 1) + 1] = 1.0;

  double v[11][20];
  double tau[11];
  for (int i = 0; i < 11; ++i) {
    double alpha = L[i][i];
    double xn2 = 0.0;
    for (int l = i + 1; l < 20; ++l) xn2 += L[i][l] * L[i][l];
    double xnorm = sqrt(xn2);
    for (int l = 0; l < 20; ++l) v[i][l] = 0.0;
    v[i][i] = 1.0;
    if (xnorm == 0.0) {
      tau[i] = 0.0;
    } else {
      double beta = sqrt(alpha * alpha + xn2);
      if (alpha >= 0.0) beta = -beta;        // dlarfg: beta = -sign(alpha)*norm
      tau[i] = (beta - alpha) / beta;
      double sc = 1.0 / (alpha - beta);
      for (int l = i + 1; l < 20; ++l) v[i][l] = L[i][l] * sc;
      L[i][i] = beta;
      for (int j = i + 1; j < 11; ++j) {
        double w = 0.0;
        for (int l = i; l < 20; ++l) w += L[j][l] * v[i][l];
        w *= tau[i];
        for (int l = i; l < 20; ++l) L[j][l] -= w * v[i][l];
      }
    }
  }
  for (int j = 11; j < 20; ++j) {
    double q[20];
    for (int l = 0; l < 20; ++l) q[l] = 0.0;
    q[j] = 1.0;
    for (int i = 10; i >= 0; --i) {
      double w = 0.0;
      for (int l = i; l < 20; ++l) w += v[i][l] * q[l];
      w *= tau[i];
      for (int l = i; l < 20; ++l) q[l] -= w * v[i][l];
    }
    for (int l = 0; l < 20; ++l) bs->Bt[j - 11][l] = (float)q[l];
  }
}

// Fold W3B[r][l] = sum_t w3[r*9+t]*Bt[t][l] (10x20) and b3B[l] = sum_t b3[t]*Bt[t][l]
// per MLP into ws: [m1: 200 W + 20 b][m2: 200 W + 20 b] floats.
__global__ void fold_kernel(const float* __restrict__ w3_1, const float* __restrict__ b3_1,
                            const float* __restrict__ w3_2, const float* __restrict__ b3_2,
                            float* __restrict__ ws, Basis bb) {
  for (int f = threadIdx.x; f < 440; f += THREADS) {
    int m = f / 220;
    int j = f % 220;
    const float* w3 = (m == 0) ? w3_1 : w3_2;
    const float* b3 = (m == 0) ? b3_1 : b3_2;
    float val = 0.0f;
    if (j < 200) {
      int r = j / 20, l = j % 20;
      for (int t = 0; t < DDIM; ++t) val += w3[r * DDIM + t] * bb.Bt[t][l];
    } else {
      int l = j - 200;
      for (int t = 0; t < DDIM; ++t) val += b3[t] * bb.Bt[t][l];
    }
    ws[f] = val;
  }
}

// MLP (1->10->10->10) then A = h2 @ W3B + b3B written to this thread's LDS column.
__device__ __forceinline__ void mlp_A(float xin,
    const float* __restrict__ w0, const float* __restrict__ b0,
    const float* __restrict__ w1, const float* __restrict__ b1,
    const float* __restrict__ w2, const float* __restrict__ b2,
    const float* __restrict__ wbf,     // 220 floats: 100 f32x2 W3B pairs + 10 f32x2 b3B pairs
    f32x2* abcol) {
  const f32x2* w0p = (const f32x2*)w0;
  const f32x2* b0p = (const f32x2*)b0;
  const f32x2* w1p = (const f32x2*)w1;
  const f32x2* b1p = (const f32x2*)b1;
  const f32x2* w2p = (const f32x2*)w2;
  const f32x2* b2p = (const f32x2*)b2;
  const f32x2* WB  = (const f32x2*)wbf;

  f32x2 h0[5], h1[5], h2[5];
  f32x2 xx = {xin, xin};
#pragma unroll
  for (int p = 0; p < 5; ++p) h0[p] = fma2(xx, w0p[p], b0p[p]);

#pragma unroll
  for (int p = 0; p < 5; ++p) h1[p] = b1p[p];
#pragma unroll
  for (int r = 0; r < 10; ++r) {
    float h = h0[r >> 1][r & 1];
    f32x2 hh = {h, h};
#pragma unroll
    for (int p = 0; p < 5; ++p) h1[p] = fma2(hh, w1p[r * 5 + p], h1[p]);
  }
  f32x2 zero = {0.0f, 0.0f};
#pragma unroll
  for (int p = 0; p < 5; ++p) h1[p] = max2(h1[p], zero);

#pragma unroll
  for (int p = 0; p < 5; ++p) h2[p] = b2p[p];
#pragma unroll
  for (int r = 0; r < 10; ++r) {
    float h = h1[r >> 1][r & 1];
    f32x2 hh = {h, h};
#pragma unroll
    for (int p = 0; p < 5; ++p) h2[p] = fma2(hh, w2p[r * 5 + p], h2[p]);
  }
#pragma unroll
  for (int p = 0; p < 5; ++p) h2[p] = max2(h2[p], zero);

  f32x2 acc[NCELL];
#pragma unroll
  for (int l = 0; l < NCELL; ++l) acc[l] = WB[100 + l];   // b3B pairs
#pragma unroll
  for (int r = 0; r < 10; ++r) {
    float h = h2[r >> 1][r & 1];
    f32x2 hh = {h, h};
#pragma unroll
    for (int l = 0; l < NCELL; ++l) acc[l] = fma2(hh, WB[r * 10 + l], acc[l]);
  }
#pragma unroll
  for (int l = 0; l < NCELL; ++l) abcol[l * THREADS] = acc[l];
}

// Cell-hop loop, trans-minimized:
//  - exp/phi-evolve deferred to ONE post-loop step (exp only used by the
//    terminal iteration; crossing iterations take phi=xc). In-loop records
//    trem at the terminal; final cell's (a,b) re-read from LDS after.
//  - ld accumulates the log-ratio l directly on crossings (== a*thit to 2ulp);
//    terminal contribution a*trem added post-loop. lin lanes: l ~= a*thit too.
//  - rcp(sb) lin path behind wave-uniform __any(lin) (never taken in practice).
//  - frozen-lane detection: an exact no-op crossing (xc==phi && cn==c, i.e.
//    domain-edge ping-pong) can never change state again; count it as done for
//    the early-exit vote. Reference burns all 10 scan steps on these; output
//    is identical (only dead t/ld accumulation of ~1e-7/iter is skipped).
__device__ __forceinline__ void flow_dev(float x0, const f32x2* abcol,
                                         float& zo, float& ldo) {
  float phi = x0;
  float t = 1.0f;
  float ld = 0.0f;
  float trem = 0.0f;
  int c = (int)(x0 * 10.0f);
  c = c < 0 ? 0 : (c > 9 ? 9 : c);
  for (int it = 0; it < NCELL; ++it) {
    f32x2 ab = abcol[c * THREADS];
    float a = ab[0], b = ab[1];
    float v = fmaf(a, phi, b);
    float rv = __builtin_amdgcn_rcpf(v);
    bool right = (v >= 0.0f);
    int xci = right ? (c + 1) : c;
    float xc = (float)xci * 0.1f;
    int cn = right ? (c + 1) : (c - 1);
    cn = cn < 0 ? 0 : (cn > 9 ? 9 : cn);
    float vxc = fmaf(a, xc, b);
    float ratio = fmaxf(vxc * rv, 1e-30f);
    float l = __logf(ratio);                     // v_log_f32
    bool lin = fabsf(a) < 1e-10f;
    float sa = lin ? 1.0f : a;
    float thit = l * __builtin_amdgcn_rcpf(sa);
    if (__any(lin)) {                            // wave-uniform, ~never taken
      float sb = (fabsf(b) < 1e-30f) ? 1.0f : b;
      float tl = (xc - phi) * __builtin_amdgcn_rcpf(sb);
      thit = lin ? tl : thit;
    }
    thit = (fabsf(v) < 1e-14f) ? __builtin_inff() : thit;
    bool active = t > 0.0f;
    bool cross = thit < t;
    bool ac = active && cross;
    bool term = active && !cross;
    bool frozen = ac && (xc == phi) && (cn == c);  // exact no-op crossing
    trem = term ? t : trem;
    ld += ac ? l : 0.0f;
    phi = ac ? xc : phi;
    t = active ? (cross ? (t - thit) : 0.0f) : t;
    c = ac ? cn : c;
    bool stop = (t <= 0.0f) || frozen;
    if (__all(stop)) break;
  }
  // post-loop: evolve once inside the terminal cell (reference formulas)
  f32x2 abf = abcol[c * THREADS];
  float aF = abf[0], bF = abf[1];
  bool done = trem > 0.0f;
  bool linf = fabsf(aF) < 1e-10f;
  float rsaf = __builtin_amdgcn_rcpf(linf ? 1.0f : aF);
  float bsa = bF * rsaf;
  float E = __expf(aF * trem);                   // the ONLY exp in the flow
  float pnl = fmaf(phi + bsa, E, -bsa);
  float pli = fmaf(bF, trem, phi);
  float p1 = linf ? pli : pnl;
  zo = done ? p1 : phi;
  ldo = ld + (done ? aF * trem : 0.0f);
}

__global__ __launch_bounds__(THREADS, 4) void cpab2d_kernel(
    const float* __restrict__ x,
    const float* __restrict__ m1w0, const float* __restrict__ m1b0,
    const float* __restrict__ m1w1, const float* __restrict__ m1b1,
    const float* __restrict__ m1w2, const float* __restrict__ m1b2,
    const float* __restrict__ m2w0, const float* __restrict__ m2b0,
    const float* __restrict__ m2w1, const float* __restrict__ m2b1,
    const float* __restrict__ m2w2, const float* __restrict__ m2b2,
    const float* __restrict__ wsf,
    float* __restrict__ out, int n) {
  __shared__ f32x2 AB[NCELL][THREADS];   // [cell][tid] -> conflict-free dyn read
  int i = blockIdx.x * THREADS + threadIdx.x;
  if (i >= n) return;

  float2 xi = reinterpret_cast<const float2*>(x)[i];
  // xs = x[:, [1,0]]: x1 = x[:,1], x2 = x[:,0]; both clipped first
  float x2v = fminf(fmaxf(xi.x, 1e-7f), 1.0f - 1e-7f);
  float x1v = fminf(fmaxf(xi.y, 1e-7f), 1.0f - 1e-7f);

  f32x2* abcol = &AB[0][threadIdx.x];

  // theta2 = mlp(x1, m2); z2,g2 = flow(x2, theta2)
  mlp_A(x1v, m2w0, m2b0, m2w1, m2b1, m2w2, m2b2, wsf + 220, abcol);
  float z2, ld2;
  flow_dev(x2v, abcol, z2, ld2);

  // theta1 = mlp(z2, m1); z1,g1 = flow(x1, theta1)
  mlp_A(z2, m1w0, m1b0, m1w1, m1b1, m1w2, m1b2, wsf, abcol);
  float z1, ld1;
  flow_dev(x1v, abcol, z1, ld1);

  // z = [z2, z1]; log_dz_dx = [ld2, ld1]
  reinterpret_cast<float2*>(out)[i] = make_float2(z2, z1);
  reinterpret_cast<float2*>(out + 2 * (size_t)n)[i] = make_float2(ld2, ld1);
}

extern "C" void kernel_launch(void* const* d_in, const int* in_sizes, int n_in,
                              void* d_out, int out_size, void* d_ws, size_t ws_size,
                              hipStream_t stream) {
  const float* x    = (const float*)d_in[0];
  const float* m1w0 = (const float*)d_in[1];
  const float* m1b0 = (const float*)d_in[2];
  const float* m1w1 = (const float*)d_in[3];
  const float* m1b1 = (const float*)d_in[4];
  const float* m1w2 = (const float*)d_in[5];
  const float* m1b2 = (const float*)d_in[6];
  const float* m1w3 = (const float*)d_in[7];
  const float* m1b3 = (const float*)d_in[8];
  const float* m2w0 = (const float*)d_in[9];
  const float* m2b0 = (const float*)d_in[10];
  const float* m2w1 = (const float*)d_in[11];
  const float* m2b1 = (const float*)d_in[12];
  const float* m2w2 = (const float*)d_in[13];
  const float* m2b2 = (const float*)d_in[14];
  const float* m2w3 = (const float*)d_in[15];
  const float* m2b3 = (const float*)d_in[16];
  float* out = (float*)d_out;
  float* wsf = (float*)d_ws;
  int n = in_sizes[0] / 2;

  Basis bs;
  compute_basis_host(&bs);

  fold_kernel<<<1, THREADS, 0, stream>>>(m1w3, m1b3, m2w3, m2b3, wsf, bs);

  dim3 grid((n + THREADS - 1) / THREADS), block(THREADS);
  cpab2d_kernel<<<grid, block, 0, stream>>>(
      x, m1w0, m1b0, m1w1, m1b1, m1w2, m1b2,
      m2w0, m2b0, m2w1, m2b1, m2w2, m2b2,
      wsf, out, n);
}